// Round 20
// baseline (371.989 us; speedup 1.0000x reference)
//
#include <hip/hip_runtime.h>
#include <hip/hip_bf16.h>

typedef __attribute__((ext_vector_type(4))) float f32x4;
typedef __attribute__((ext_vector_type(8))) short bf16x8;
typedef unsigned short u16;

#define AS1 __attribute__((address_space(1)))
#define AS3 __attribute__((address_space(3)))

#define B_    16
#define HW_   4096
#define C_    512
#define NCTX  77
#define DCTX  768
#define NH    8
#define HD    64
#define EPSV  1e-5f

__device__ inline u16 f2bf(float f) {
    union { float f; unsigned u; } v; v.f = f;
    unsigned r = v.u + 0x7fffu + ((v.u >> 16) & 1u);
    return (u16)(r >> 16);
}

// ------- GroupNorm stats (blocks 0..511) + all weight transposes (blocks 512..5631) -------
__global__ __launch_bounds__(256) void gn_trans(const float* __restrict__ x,
                                                float* __restrict__ mean,
                                                float* __restrict__ rstd,
                                                const float* __restrict__ wq,
                                                const float* __restrict__ wk,
                                                const float* __restrict__ wv,
                                                const float* __restrict__ wo,
                                                u16* __restrict__ wqT,
                                                u16* __restrict__ wkT,
                                                u16* __restrict__ wvT,
                                                u16* __restrict__ woT) {
    if (blockIdx.x < 512) {
        int b = blockIdx.x >> 5, g = blockIdx.x & 31;
        const float* px = x + (size_t)b * HW_ * C_ + g * 16;
        float s = 0.f, ss = 0.f;
        for (int t = threadIdx.x; t < HW_ * 4; t += 256) {
            int hw = t >> 2, c4 = (t & 3) * 4;
            const float4 v = *(const float4*)(px + (size_t)hw * C_ + c4);
            s  += v.x + v.y + v.z + v.w;
            ss += v.x * v.x + v.y * v.y + v.z * v.z + v.w * v.w;
        }
        for (int off = 32; off; off >>= 1) { s += __shfl_xor(s, off); ss += __shfl_xor(ss, off); }
        __shared__ float red[2][4];
        int wv_ = threadIdx.x >> 6, lane = threadIdx.x & 63;
        if (lane == 0) { red[0][wv_] = s; red[1][wv_] = ss; }
        __syncthreads();
        if (threadIdx.x == 0) {
            float S = red[0][0] + red[0][1] + red[0][2] + red[0][3];
            float SS = red[1][0] + red[1][1] + red[1][2] + red[1][3];
            float mn = S / 65536.f;
            float var = SS / 65536.f - mn * mn;
            mean[blockIdx.x] = mn;
            rstd[blockIdx.x] = rsqrtf(var + EPSV);
        }
    } else {
        int idx = (blockIdx.x - 512) * 256 + threadIdx.x;
        if (idx < 262144) {
            int k = idx >> 9, n = idx & 511;
            wqT[(size_t)n * 512 + k] = f2bf(wq[idx]);
        } else if (idx < 655360) {
            int i = idx - 262144;
            int k = i >> 9, n = i & 511;
            wkT[(size_t)n * 768 + k] = f2bf(wk[i]);
        } else if (idx < 1048576) {
            int i = idx - 655360;
            int k = i >> 9, n = i & 511;
            wvT[(size_t)n * 768 + k] = f2bf(wv[i]);
        } else if (idx < 1310720) {
            int i = idx - 1048576;
            int k = i >> 9, n = i & 511;
            woT[(size_t)n * 512 + k] = f2bf(wo[i]);
        }
    }
}

// ======= Q-proj (GN-fused, BK=32, 32KB LDS, 4 blocks/CU) for blocks < 2048;
//         K/V projections for blocks 2048..2127 (shared 32 KB pool) =======
__global__ __launch_bounds__(256, 4) void gemm_fusedq(const float* __restrict__ x,
                                                      const float* __restrict__ mean,
                                                      const float* __restrict__ rstd,
                                                      const float* __restrict__ gns,
                                                      const float* __restrict__ gnb,
                                                      const u16* __restrict__ Bt,
                                                      const float* __restrict__ bias,
                                                      u16* __restrict__ out,
                                                      const float* __restrict__ ctx,
                                                      const u16* __restrict__ wkT,
                                                      const u16* __restrict__ wvT,
                                                      const float* __restrict__ bk,
                                                      const float* __restrict__ bv,
                                                      u16* __restrict__ kb,
                                                      u16* __restrict__ vb) {
    __shared__ __align__(16) u16 POOL[16384];   // 32 KB
    int tid = threadIdx.x, lane = tid & 63, wid = tid >> 6;
    int q = lane >> 4, r16 = lane & 15;

    if (blockIdx.x >= 2048) {
        // ---------------- K/V projection branch (80 blocks: 8 x 10) ----------------
        constexpr int M = 1232, K = 768;
        u16 (*As)[40] = (u16(*)[40])&POOL[0];        // 128x40 = 10240 B
        u16 (*Bs)[40] = (u16(*)[40])&POOL[5120];     // 10240 B (total 20480 <= 32768)
        int idx = blockIdx.x - 2048;
        int bx = idx & 7, byk = idx >> 3;
        const u16* Btl = (bx < 4) ? wkT : wvT;
        const float* bi = (bx < 4) ? bk : bv;
        u16* o = (bx < 4) ? kb : vb;
        int wm = wid >> 1, wn = wid & 1;
        int row0 = byk * 128, col0 = (bx & 3) * 128;

        f32x4 acc[4][4];
#pragma unroll
        for (int i = 0; i < 4; i++)
#pragma unroll
            for (int j = 0; j < 4; j++) acc[i][j] = (f32x4){0.f, 0.f, 0.f, 0.f};

        for (int k0 = 0; k0 < K; k0 += 32) {
#pragma unroll
            for (int it = 0; it < 2; ++it) {
                int e = it * 256 + tid;
                int rr = e >> 2, kc = (e & 3) * 8;
                int ga = row0 + rr; if (ga > M - 1) ga = M - 1;
                float4 a0 = *(const float4*)(ctx + (size_t)ga * K + k0 + kc);
                float4 a1 = *(const float4*)(ctx + (size_t)ga * K + k0 + kc + 4);
                bf16x8 av;
                av[0] = (short)f2bf(a0.x); av[1] = (short)f2bf(a0.y);
                av[2] = (short)f2bf(a0.z); av[3] = (short)f2bf(a0.w);
                av[4] = (short)f2bf(a1.x); av[5] = (short)f2bf(a1.y);
                av[6] = (short)f2bf(a1.z); av[7] = (short)f2bf(a1.w);
                *(bf16x8*)&As[rr][kc] = av;
                int gb = col0 + rr;
                bf16x8 bv8 = *(const bf16x8*)(Btl + (size_t)gb * K + k0 + kc);
                *(bf16x8*)&Bs[rr][kc] = bv8;
            }
            __syncthreads();
            bf16x8 afr[4], bfr[4];
#pragma unroll
            for (int mi = 0; mi < 4; mi++) afr[mi] = *(const bf16x8*)&As[wm * 64 + mi * 16 + r16][q * 8];
#pragma unroll
            for (int ni = 0; ni < 4; ni++) bfr[ni] = *(const bf16x8*)&Bs[wn * 64 + ni * 16 + r16][q * 8];
#pragma unroll
            for (int mi = 0; mi < 4; mi++)
#pragma unroll
                for (int ni = 0; ni < 4; ni++)
                    acc[mi][ni] = __builtin_amdgcn_mfma_f32_16x16x32_bf16(afr[mi], bfr[ni], acc[mi][ni], 0, 0, 0);
            __syncthreads();
        }

#pragma unroll
        for (int mi = 0; mi < 4; mi++) {
#pragma unroll
            for (int rr = 0; rr < 4; rr++) {
                int grow = row0 + wm * 64 + mi * 16 + q * 4 + rr;
                if (grow >= M) continue;
#pragma unroll
                for (int ni = 0; ni < 4; ni++) {
                    int gcol = col0 + wn * 64 + ni * 16 + r16;
                    float v = acc[mi][ni][rr] + bi[gcol];
                    o[(size_t)grow * 512 + gcol] = f2bf(v);
                }
            }
        }
        return;
    }

    // ---------------- fused-Q branch: BK=32, dbuf 2x(8+8) KB ----------------
    constexpr int K = 512;
    u16* LA = &POOL[0];          // [2][4096] elems
    u16* LB = &POOL[8192];       // [2][4096]
    int wr = wid >> 1, wc = wid & 1;

    int orig = blockIdx.x;
    int wg = (orig & 7) * 256 + (orig >> 3);
    int bx = wg & 3, by = wg >> 2;
    int row0 = by * 128, col0 = bx * 128;

    // B staging (gload_lds, source pre-swizzled; rows srow, srow+64)
    int srB = tid >> 2;
    int cB = (tid & 3) ^ (srB & 3);
    const u16* gB = Bt + (size_t)(col0 + srB) * K + cB * 8;
    const int lo = tid * 8;

    // A path: thread covers rows r0l, r0l+1; 8-col chunk c4
    int c4 = tid & 3;
    int r0l = (tid >> 2) * 2;
    const float* xb = x + (size_t)(row0 + r0l) * 512 + c4 * 8;
    int bg0 = (row0 >> 12) * 32;

    f32x4 acc[4][4];
#pragma unroll
    for (int i = 0; i < 4; i++)
#pragma unroll
        for (int j = 0; j < 4; j++) acc[i][j] = (f32x4){0.f, 0.f, 0.f, 0.f};

    float4 ar0, ar1, ar2, ar3;
    float mn, rs;
    float4 s0v, s1v, b0v, b1v;

#define LOADA(kt) do {                                      \
    ar0 = *(const float4*)(xb + (kt) * 32);                 \
    ar1 = *(const float4*)(xb + (kt) * 32 + 4);             \
    ar2 = *(const float4*)(xb + (kt) * 32 + 512);           \
    ar3 = *(const float4*)(xb + (kt) * 32 + 516);           \
  } while (0)

#define LOADP(kt) do { int c0_ = (kt) * 32 + c4 * 8; int bg_ = bg0 + (c0_ >> 4);  \
    mn = mean[bg_]; rs = rstd[bg_];                                               \
    s0v = *(const float4*)(gns + c0_); s1v = *(const float4*)(gns + c0_ + 4);     \
    b0v = *(const float4*)(gnb + c0_); b1v = *(const float4*)(gnb + c0_ + 4);     \
  } while (0)

#define WRITEA(nbuf) do {                                                         \
    float m_[8], a_[8];                                                           \
    m_[0]=rs*s0v.x; m_[1]=rs*s0v.y; m_[2]=rs*s0v.z; m_[3]=rs*s0v.w;               \
    m_[4]=rs*s1v.x; m_[5]=rs*s1v.y; m_[6]=rs*s1v.z; m_[7]=rs*s1v.w;               \
    a_[0]=b0v.x-mn*m_[0]; a_[1]=b0v.y-mn*m_[1];                                   \
    a_[2]=b0v.z-mn*m_[2]; a_[3]=b0v.w-mn*m_[3];                                   \
    a_[4]=b1v.x-mn*m_[4]; a_[5]=b1v.y-mn*m_[5];                                   \
    a_[6]=b1v.z-mn*m_[6]; a_[7]=b1v.w-mn*m_[7];                                   \
    bf16x8 p0_, p1_;                                                              \
    p0_[0]=(short)f2bf(ar0.x*m_[0]+a_[0]); p0_[1]=(short)f2bf(ar0.y*m_[1]+a_[1]); \
    p0_[2]=(short)f2bf(ar0.z*m_[2]+a_[2]); p0_[3]=(short)f2bf(ar0.w*m_[3]+a_[3]); \
    p0_[4]=(short)f2bf(ar1.x*m_[4]+a_[4]); p0_[5]=(short)f2bf(ar1.y*m_[5]+a_[5]); \
    p0_[6]=(short)f2bf(ar1.z*m_[6]+a_[6]); p0_[7]=(short)f2bf(ar1.w*m_[7]+a_[7]); \
    p1_[0]=(short)f2bf(ar2.x*m_[0]+a_[0]); p1_[1]=(short)f2bf(ar2.y*m_[1]+a_[1]); \
    p1_[2]=(short)f2bf(ar2.z*m_[2]+a_[2]); p1_[3]=(short)f2bf(ar2.w*m_[3]+a_[3]); \
    p1_[4]=(short)f2bf(ar3.x*m_[4]+a_[4]); p1_[5]=(short)f2bf(ar3.y*m_[5]+a_[5]); \
    p1_[6]=(short)f2bf(ar3.z*m_[6]+a_[6]); p1_[7]=(short)f2bf(ar3.w*m_[7]+a_[7]); \
    *(bf16x8*)&LA[(nbuf) * 4096 + r0l * 32 + ((c4 ^ (r0l & 3)) * 8)] = p0_;       \
    *(bf16x8*)&LA[(nbuf) * 4096 + (r0l + 1) * 32 + ((c4 ^ ((r0l + 1) & 3)) * 8)] = p1_; \
  } while (0)

#define STG_B(kt) do { int sl_ = ((kt) & 1) * 4096;                                    \
    __builtin_amdgcn_global_load_lds((const AS1 void*)(gB + (kt) * 32),                \
                                     (AS3 void*)(&LB[sl_ + lo]), 16, 0, 0);            \
    __builtin_amdgcn_global_load_lds((const AS1 void*)(gB + (kt) * 32 + (size_t)64 * K), \
                                     (AS3 void*)(&LB[sl_ + 2048 + lo]), 16, 0, 0);     \
  } while (0)

#define COMPUTE(sl) do {                                                               \
    bf16x8 afr[4], bfr[4];                                                             \
    const int ch_ = (q ^ (r16 & 3)) * 8;                                               \
    _Pragma("unroll")                                                                  \
    for (int mi = 0; mi < 4; mi++)                                                     \
        afr[mi] = *(const bf16x8*)&LA[(sl) * 4096 + (wr * 64 + mi * 16 + r16) * 32 + ch_]; \
    _Pragma("unroll")                                                                  \
    for (int ni = 0; ni < 4; ni++)                                                     \
        bfr[ni] = *(const bf16x8*)&LB[(sl) * 4096 + (wc * 64 + ni * 16 + r16) * 32 + ch_]; \
    __builtin_amdgcn_s_setprio(1);                                                     \
    _Pragma("unroll")                                                                  \
    for (int mi = 0; mi < 4; mi++)                                                     \
      _Pragma("unroll")                                                                \
      for (int ni = 0; ni < 4; ni++)                                                   \
        acc[mi][ni] = __builtin_amdgcn_mfma_f32_16x16x32_bf16(afr[mi], bfr[ni], acc[mi][ni], 0, 0, 0); \
    __builtin_amdgcn_s_setprio(0);                                                     \
  } while (0)

    // prologue: tile 0 (A 4 + P 6 + B 2)
    LOADA(0); LOADP(0);
    asm volatile("" ::: "memory");
    STG_B(0);
    asm volatile("s_waitcnt vmcnt(2)" ::: "memory");   // A0+P0 landed; B0 in flight
    WRITEA(0);
    asm volatile("s_waitcnt lgkmcnt(0)" ::: "memory");

#pragma unroll
    for (int t = 0; t < 15; ++t) {
        const int buf = t & 1;
        LOADA(t + 1); LOADP(t + 1);
        asm volatile("" ::: "memory");
        STG_B(t + 1);
        asm volatile("s_waitcnt vmcnt(12)" ::: "memory");  // drain B(t); 12 newer stay
        __builtin_amdgcn_s_barrier();
        asm volatile("" ::: "memory");
        COMPUTE(buf);
        asm volatile("s_waitcnt vmcnt(2)" ::: "memory");   // A+P(t+1) landed; B(t+1) in flight
        WRITEA(buf ^ 1);
        asm volatile("s_waitcnt lgkmcnt(0)" ::: "memory");
        __builtin_amdgcn_s_barrier();
        asm volatile("" ::: "memory");
    }
    asm volatile("s_waitcnt vmcnt(0) lgkmcnt(0)" ::: "memory");
    __builtin_amdgcn_s_barrier();
    asm volatile("" ::: "memory");
    COMPUTE(1);                                            // tile 15
#undef LOADA
#undef LOADP
#undef WRITEA
#undef STG_B
#undef COMPUTE

#pragma unroll
    for (int mi = 0; mi < 4; mi++) {
#pragma unroll
        for (int rr = 0; rr < 4; rr++) {
            int grow = row0 + wr * 64 + mi * 16 + q * 4 + rr;
#pragma unroll
            for (int ni = 0; ni < 4; ni++) {
                int gcol = col0 + wc * 64 + ni * 16 + r16;
                float v = acc[mi][ni][rr] + bias[gcol];
                out[(size_t)grow * 512 + gcol] = f2bf(v);
            }
        }
    }
}

// ------- O-proj GEMM (r13/r17 best): 128x128, BK=32, dbuf 32KB LDS, __launch_bounds__(256,4) -------
__global__ __launch_bounds__(256, 4) void gemm_ring(const u16* __restrict__ A,
                                                    const u16* __restrict__ Bt,
                                                    const float* __restrict__ bias,
                                                    const float* __restrict__ res,
                                                    float* __restrict__ out) {
    constexpr int K = 512;
    __shared__ __align__(16) u16 LA[2][4096];
    __shared__ __align__(16) u16 LB[2][4096];
    int tid = threadIdx.x, lane = tid & 63, wid = tid >> 6;
    int wr = wid >> 1, wc = wid & 1;
    int q = lane >> 4, r16 = lane & 15;

    int orig = blockIdx.x;
    int wg = (orig & 7) * 256 + (orig >> 3);
    int bx = wg & 3, by = wg >> 2;
    int row0 = by * 128, col0 = bx * 128;

    int srow = tid >> 2;
    int schunk = (tid & 3) ^ (srow & 3);
    const u16* gA = A + (size_t)(row0 + srow) * K + schunk * 8;
    const u16* gB = Bt + (size_t)(col0 + srow) * K + schunk * 8;
    const int lo = tid * 8;

    f32x4 acc[4][4];
#pragma unroll
    for (int i = 0; i < 4; i++)
#pragma unroll
        for (int j = 0; j < 4; j++) acc[i][j] = (f32x4){0.f, 0.f, 0.f, 0.f};

#define STG(kt) do { int sl_ = (kt) & 1;                                              \
    __builtin_amdgcn_global_load_lds((const AS1 void*)(gA + (kt) * 32),               \
                                     (AS3 void*)(&LA[sl_][lo]), 16, 0, 0);            \
    __builtin_amdgcn_global_load_lds((const AS1 void*)(gA + (kt) * 32 + (size_t)64 * K), \
                                     (AS3 void*)(&LA[sl_][2048 + lo]), 16, 0, 0);     \
    __builtin_amdgcn_global_load_lds((const AS1 void*)(gB + (kt) * 32),               \
                                     (AS3 void*)(&LB[sl_][lo]), 16, 0, 0);            \
    __builtin_amdgcn_global_load_lds((const AS1 void*)(gB + (kt) * 32 + (size_t)64 * K), \
                                     (AS3 void*)(&LB[sl_][2048 + lo]), 16, 0, 0);     \
  } while (0)

#define COMPUTE(sl) do {                                                              \
    bf16x8 afr[4], bfr[4];                                                            \
    const int ch_ = (q ^ (r16 & 3)) * 8;                                              \
    _Pragma("unroll")                                                                 \
    for (int mi = 0; mi < 4; mi++)                                                    \
        afr[mi] = *(const bf16x8*)&LA[sl][(wr * 64 + mi * 16 + r16) * 32 + ch_];      \
    _Pragma("unroll")                                                                 \
    for (int ni = 0; ni < 4; ni++)                                                    \
        bfr[ni] = *(const bf16x8*)&LB[sl][(wc * 64 + ni * 16 + r16) * 32 + ch_];      \
    __builtin_amdgcn_s_setprio(1);                                                    \
    _Pragma("unroll")                                                                 \
    for (int mi = 0; mi < 4; mi++)                                                    \
      _Pragma("unroll")                                                               \
      for (int ni = 0; ni < 4; ni++)                                                  \
        acc[mi][ni] = __builtin_amdgcn_mfma_f32_16x16x32_bf16(afr[mi], bfr[ni], acc[mi][ni], 0, 0, 0); \
    __builtin_amdgcn_s_setprio(0);                                                    \
  } while (0)

    STG(0);
#pragma unroll
    for (int t = 0; t < 15; ++t) {
        STG(t + 1);
        asm volatile("s_waitcnt vmcnt(4)" ::: "memory");
        asm volatile("s_barrier" ::: "memory");
        COMPUTE(t & 1);
        asm volatile("s_barrier" ::: "memory");
    }
    asm volatile("s_waitcnt vmcnt(0)" ::: "memory");
    asm volatile("s_barrier" ::: "memory");
    COMPUTE(1);
#undef STG
#undef COMPUTE

#pragma unroll
    for (int mi = 0; mi < 4; mi++) {
#pragma unroll
        for (int rr = 0; rr < 4; rr++) {
            int grow = row0 + wr * 64 + mi * 16 + q * 4 + rr;
#pragma unroll
            for (int ni = 0; ni < 4; ni++) {
                int gcol = col0 + wc * 64 + ni * 16 + r16;
                float v = acc[mi][ni][rr] + bias[gcol];
                size_t idx = (size_t)grow * 512 + gcol;
                out[idx] = v + res[idx];
            }
        }
    }
}

// ------- MFMA cross-attention: 8 Q-tiles per block (r13 best config), K/V staged once -------
__global__ __launch_bounds__(256) void attn_mfma(const u16* __restrict__ Qb,
                                                 const u16* __restrict__ Kb,
                                                 const u16* __restrict__ Vb,
                                                 u16* __restrict__ Ob) {
    __shared__ __align__(16) u16 Ks[80][72];    // [ctx][d]
    __shared__ __align__(16) u16 VT[64][104];   // [d][ctx]
    __shared__ __align__(16) u16 Ps[64][104];   // [qrow_local][ctx]
    int tid = threadIdx.x, lane = tid & 63, wv = tid >> 6;
    int q = lane >> 4, r16 = lane & 15;
    int tile0 = blockIdx.x * 8;
    int bh = blockIdx.y;
    int b = bh >> 3, h = bh & 7;

    {
        unsigned* p0 = (unsigned*)&Ks[0][0];
        for (int i = tid; i < 2880; i += 256) p0[i] = 0u;
        unsigned* p1 = (unsigned*)&VT[0][0];
        for (int i = tid; i < 3328; i += 256) p1[i] = 0u;
        unsigned* p2 = (unsigned*)&Ps[0][0];
        for (int i = tid; i < 3328; i += 256) p2[i] = 0u;
    }
    __syncthreads();

    size_t kvbase = ((size_t)b * NCTX) * C_ + h * HD;
    for (int c = tid; c < NCTX * 8; c += 256) {
        int j = c >> 3, d8 = (c & 7) * 8;
        *(bf16x8*)&Ks[j][d8] = *(const bf16x8*)(Kb + kvbase + (size_t)j * C_ + d8);
    }
    for (int t = tid; t < NCTX * 64; t += 256) {
        int j = t >> 6, d = t & 63;
        VT[d][j] = Vb[kvbase + (size_t)j * C_ + d];
    }
    __syncthreads();

    const size_t tstep = (size_t)64 * C_;
    const u16* qp = Qb + ((size_t)b * HW_ + wv * 16 + r16) * C_ + h * HD + q * 8;
    bool v4 = (r16 < NCTX - 64);

    bf16x8 qc0 = *(const bf16x8*)(qp + (size_t)tile0 * tstep);
    bf16x8 qc1 = *(const bf16x8*)(qp + (size_t)tile0 * tstep + 32);

    for (int it = 0; it < 8; ++it) {
        int tile = tile0 + it;
        bf16x8 qn0 = qc0, qn1 = qc1;
        if (it < 7) {
            qn0 = *(const bf16x8*)(qp + (size_t)(tile + 1) * tstep);
            qn1 = *(const bf16x8*)(qp + (size_t)(tile + 1) * tstep + 32);
        }

        f32x4 accs[5];
#pragma unroll
        for (int nt = 0; nt < 5; ++nt) accs[nt] = (f32x4){0.f, 0.f, 0.f, 0.f};
#pragma unroll
        for (int nt = 0; nt < 5; ++nt) {
            bf16x8 kf = *(const bf16x8*)&Ks[nt * 16 + r16][q * 8];
            accs[nt] = __builtin_amdgcn_mfma_f32_16x16x32_bf16(qc0, kf, accs[nt], 0, 0, 0);
        }
#pragma unroll
        for (int nt = 0; nt < 5; ++nt) {
            bf16x8 kf = *(const bf16x8*)&Ks[nt * 16 + r16][32 + q * 8];
            accs[nt] = __builtin_amdgcn_mfma_f32_16x16x32_bf16(qc1, kf, accs[nt], 0, 0, 0);
        }

#pragma unroll
        for (int r = 0; r < 4; ++r) {
            float s[5];
#pragma unroll
            for (int nt = 0; nt < 5; ++nt) s[nt] = accs[nt][r] * 0.125f;
            float m = fmaxf(fmaxf(fmaxf(s[0], s[1]), fmaxf(s[2], s[3])), v4 ? s[4] : -3.0e38f);
#pragma unroll
            for (int off = 1; off < 16; off <<= 1) m = fmaxf(m, __shfl_xor(m, off));
            float e[5], sum = 0.f;
#pragma unroll
            for (int nt = 0; nt < 5; ++nt) {
                e[nt] = (nt < 4 || v4) ? __expf(s[nt] - m) : 0.f;
                sum += e[nt];
            }
#pragma unroll
            for (int off = 1; off < 16; off <<= 1) sum += __shfl_xor(sum, off);
            float inv = 1.0f / sum;
            int prow = wv * 16 + q * 4 + r;
#pragma unroll
            for (int nt = 0; nt < 5; ++nt)
                Ps[prow][nt * 16 + r16] = f2bf(e[nt] * inv);
        }

        f32x4 acco[4];
#pragma unroll
        for (int nt = 0; nt < 4; ++nt) acco[nt] = (f32x4){0.f, 0.f, 0.f, 0.f};
#pragma unroll
        for (int ks = 0; ks < 3; ++ks) {
            bf16x8 pf = *(const bf16x8*)&Ps[wv * 16 + r16][ks * 32 + q * 8];
#pragma unroll
            for (int nt = 0; nt < 4; ++nt) {
                bf16x8 vf = *(const bf16x8*)&VT[nt * 16 + r16][ks * 32 + q * 8];
                acco[nt] = __builtin_amdgcn_mfma_f32_16x16x32_bf16(pf, vf, acco[nt], 0, 0, 0);
            }
        }

        int row0 = tile * 64 + wv * 16;
#pragma unroll
        for (int nt = 0; nt < 4; ++nt)
#pragma unroll
            for (int r = 0; r < 4; ++r) {
                int row = row0 + q * 4 + r;
                int col = h * HD + nt * 16 + r16;
                Ob[((size_t)b * HW_ + row) * C_ + col] = f2bf(acco[nt][r]);
            }
        qc0 = qn0; qc1 = qn1;
    }
}

extern "C" void kernel_launch(void* const* d_in, const int* in_sizes, int n_in,
                              void* d_out, int out_size, void* d_ws, size_t ws_size,
                              hipStream_t stream) {
    const float* x   = (const float*)d_in[0];
    const float* ctx = (const float*)d_in[1];
    const float* gns = (const float*)d_in[2];
    const float* gnb = (const float*)d_in[3];
    const float* wq  = (const float*)d_in[4];
    const float* bq  = (const float*)d_in[5];
    const float* wk  = (const float*)d_in[6];
    const float* bk  = (const float*)d_in[7];
    const float* wv  = (const float*)d_in[8];
    const float* bv  = (const float*)d_in[9];
    const float* wo  = (const float*)d_in[10];
    const float* bo  = (const float*)d_in[11];

    char* ws = (char*)d_ws;
    float* mean = (float*)(ws + 0);          // 512 f
    float* rstd = (float*)(ws + 2048);       // 512 f
    u16* wqT  = (u16*)(ws + 4096);           // 512*512
    u16* wkT  = (u16*)(ws + 528384);         // 512*768
    u16* wvT  = (u16*)(ws + 1314816);        // 512*768
    u16* woT  = (u16*)(ws + 2101248);        // 512*512
    u16* aob  = (u16*)(ws + 4517888);        // 65536*512 (attn out)
    u16* qb   = (u16*)(ws + 71626752);       // 65536*512
    u16* kb   = (u16*)(ws + 138735616);      // 1232*512
    u16* vb   = (u16*)(ws + 139997184);      // 1232*512

    gn_trans<<<5632, 256, 0, stream>>>(x, mean, rstd, wq, wk, wv, wo, wqT, wkT, wvT, woT);

    gemm_fusedq<<<2128, 256, 0, stream>>>(x, mean, rstd, gns, gnb, wqT, bq, qb,
                                          ctx, wkT, wvT, bk, bv, kb, vb);

    attn_mfma<<<dim3(8, 128), 256, 0, stream>>>(qb, kb, vb, aob);

    gemm_ring<<<2048, 256, 0, stream>>>(aob, woT, bo, x, (float*)d_out);
}

// Round 21
// 278.865 us; speedup vs baseline: 1.3339x; 1.3339x over previous
//
#include <hip/hip_runtime.h>
#include <hip/hip_bf16.h>

typedef __attribute__((ext_vector_type(4))) float f32x4;
typedef __attribute__((ext_vector_type(8))) short bf16x8;
typedef unsigned short u16;

#define AS1 __attribute__((address_space(1)))
#define AS3 __attribute__((address_space(3)))

#define B_    16
#define HW_   4096
#define C_    512
#define NCTX  77
#define DCTX  768
#define NH    8
#define HD    64
#define EPSV  1e-5f

__device__ inline u16 f2bf(float f) {
    union { float f; unsigned u; } v; v.f = f;
    unsigned r = v.u + 0x7fffu + ((v.u >> 16) & 1u);
    return (u16)(r >> 16);
}

// ------- GroupNorm stats (blocks 0..511) + all weight transposes (blocks 512..5631) -------
__global__ __launch_bounds__(256) void gn_trans(const float* __restrict__ x,
                                                float* __restrict__ mean,
                                                float* __restrict__ rstd,
                                                const float* __restrict__ wq,
                                                const float* __restrict__ wk,
                                                const float* __restrict__ wv,
                                                const float* __restrict__ wo,
                                                u16* __restrict__ wqT,
                                                u16* __restrict__ wkT,
                                                u16* __restrict__ wvT,
                                                u16* __restrict__ woT) {
    if (blockIdx.x < 512) {
        int b = blockIdx.x >> 5, g = blockIdx.x & 31;
        const float* px = x + (size_t)b * HW_ * C_ + g * 16;
        float s = 0.f, ss = 0.f;
        for (int t = threadIdx.x; t < HW_ * 4; t += 256) {
            int hw = t >> 2, c4 = (t & 3) * 4;
            const float4 v = *(const float4*)(px + (size_t)hw * C_ + c4);
            s  += v.x + v.y + v.z + v.w;
            ss += v.x * v.x + v.y * v.y + v.z * v.z + v.w * v.w;
        }
        for (int off = 32; off; off >>= 1) { s += __shfl_xor(s, off); ss += __shfl_xor(ss, off); }
        __shared__ float red[2][4];
        int wv_ = threadIdx.x >> 6, lane = threadIdx.x & 63;
        if (lane == 0) { red[0][wv_] = s; red[1][wv_] = ss; }
        __syncthreads();
        if (threadIdx.x == 0) {
            float S = red[0][0] + red[0][1] + red[0][2] + red[0][3];
            float SS = red[1][0] + red[1][1] + red[1][2] + red[1][3];
            float mn = S / 65536.f;
            float var = SS / 65536.f - mn * mn;
            mean[blockIdx.x] = mn;
            rstd[blockIdx.x] = rsqrtf(var + EPSV);
        }
    } else {
        int idx = (blockIdx.x - 512) * 256 + threadIdx.x;
        if (idx < 262144) {
            int k = idx >> 9, n = idx & 511;
            wqT[(size_t)n * 512 + k] = f2bf(wq[idx]);
        } else if (idx < 655360) {
            int i = idx - 262144;
            int k = i >> 9, n = i & 511;
            wkT[(size_t)n * 768 + k] = f2bf(wk[i]);
        } else if (idx < 1048576) {
            int i = idx - 655360;
            int k = i >> 9, n = i & 511;
            wvT[(size_t)n * 768 + k] = f2bf(wv[i]);
        } else if (idx < 1310720) {
            int i = idx - 1048576;
            int k = i >> 9, n = i & 511;
            woT[(size_t)n * 512 + k] = f2bf(wo[i]);
        }
    }
}

// ======= Q-proj (GN-fused) for blocks < 2048; K/V projections for blocks 2048..2127 =======
// Shared 64 KB LDS pool carved per branch.
__global__ __launch_bounds__(256, 2) void gemm_fusedq(const float* __restrict__ x,
                                                      const float* __restrict__ mean,
                                                      const float* __restrict__ rstd,
                                                      const float* __restrict__ gns,
                                                      const float* __restrict__ gnb,
                                                      const u16* __restrict__ Bt,
                                                      const float* __restrict__ bias,
                                                      u16* __restrict__ out,
                                                      const float* __restrict__ ctx,
                                                      const u16* __restrict__ wkT,
                                                      const u16* __restrict__ wvT,
                                                      const float* __restrict__ bk,
                                                      const float* __restrict__ bv,
                                                      u16* __restrict__ kb,
                                                      u16* __restrict__ vb) {
    __shared__ __align__(16) u16 POOL[32768];   // 64 KB
    int tid = threadIdx.x, lane = tid & 63, wid = tid >> 6;
    int q = lane >> 4, r16 = lane & 15;

    if (blockIdx.x >= 2048) {
        // ---------------- K/V projection branch (80 blocks: 8 x 10) ----------------
        constexpr int M = 1232, K = 768;
        u16 (*As)[40] = (u16(*)[40])&POOL[0];        // 128x40
        u16 (*Bs)[40] = (u16(*)[40])&POOL[5120];
        int idx = blockIdx.x - 2048;
        int bx = idx & 7, byk = idx >> 3;
        const u16* Btl = (bx < 4) ? wkT : wvT;
        const float* bi = (bx < 4) ? bk : bv;
        u16* o = (bx < 4) ? kb : vb;
        int wm = wid >> 1, wn = wid & 1;
        int row0 = byk * 128, col0 = (bx & 3) * 128;

        f32x4 acc[4][4];
#pragma unroll
        for (int i = 0; i < 4; i++)
#pragma unroll
            for (int j = 0; j < 4; j++) acc[i][j] = (f32x4){0.f, 0.f, 0.f, 0.f};

        for (int k0 = 0; k0 < K; k0 += 32) {
#pragma unroll
            for (int it = 0; it < 2; ++it) {
                int e = it * 256 + tid;
                int rr = e >> 2, kc = (e & 3) * 8;
                int ga = row0 + rr; if (ga > M - 1) ga = M - 1;
                float4 a0 = *(const float4*)(ctx + (size_t)ga * K + k0 + kc);
                float4 a1 = *(const float4*)(ctx + (size_t)ga * K + k0 + kc + 4);
                bf16x8 av;
                av[0] = (short)f2bf(a0.x); av[1] = (short)f2bf(a0.y);
                av[2] = (short)f2bf(a0.z); av[3] = (short)f2bf(a0.w);
                av[4] = (short)f2bf(a1.x); av[5] = (short)f2bf(a1.y);
                av[6] = (short)f2bf(a1.z); av[7] = (short)f2bf(a1.w);
                *(bf16x8*)&As[rr][kc] = av;
                int gb = col0 + rr;
                bf16x8 bv8 = *(const bf16x8*)(Btl + (size_t)gb * K + k0 + kc);
                *(bf16x8*)&Bs[rr][kc] = bv8;
            }
            __syncthreads();
            bf16x8 afr[4], bfr[4];
#pragma unroll
            for (int mi = 0; mi < 4; mi++) afr[mi] = *(const bf16x8*)&As[wm * 64 + mi * 16 + r16][q * 8];
#pragma unroll
            for (int ni = 0; ni < 4; ni++) bfr[ni] = *(const bf16x8*)&Bs[wn * 64 + ni * 16 + r16][q * 8];
#pragma unroll
            for (int mi = 0; mi < 4; mi++)
#pragma unroll
                for (int ni = 0; ni < 4; ni++)
                    acc[mi][ni] = __builtin_amdgcn_mfma_f32_16x16x32_bf16(afr[mi], bfr[ni], acc[mi][ni], 0, 0, 0);
            __syncthreads();
        }

#pragma unroll
        for (int mi = 0; mi < 4; mi++) {
#pragma unroll
            for (int rr = 0; rr < 4; rr++) {
                int grow = row0 + wm * 64 + mi * 16 + q * 4 + rr;
                if (grow >= M) continue;
#pragma unroll
                for (int ni = 0; ni < 4; ni++) {
                    int gcol = col0 + wn * 64 + ni * 16 + r16;
                    float v = acc[mi][ni][rr] + bi[gcol];
                    o[(size_t)grow * 512 + gcol] = f2bf(v);
                }
            }
        }
        return;
    }

    // ---------------- fused-Q branch (r8/r13 structure) ----------------
    constexpr int K = 512;
    u16 (*LA)[8192] = (u16(*)[8192])&POOL[0];
    u16 (*LB)[8192] = (u16(*)[8192])&POOL[16384];
    int wr = wid >> 1, wc = wid & 1;

    int orig = blockIdx.x;
    int wg = (orig & 7) * 256 + (orig >> 3);
    int bx = wg & 3, by = wg >> 2;
    int row0 = by * 128, col0 = bx * 128;

    int srow = tid >> 3;
    int schunk = (tid & 7) ^ (srow & 7);
    const u16* gB = Bt + (size_t)(col0 + srow) * K + schunk * 8;
    const int lo = tid * 8;

    int c8 = tid & 7;
    int rbase = (tid >> 3) * 4;
    const float* xb = x + (size_t)(row0 + rbase) * 512 + c8 * 8;
    int bg0 = (row0 >> 12) * 32;

    f32x4 acc[4][4];
#pragma unroll
    for (int i = 0; i < 4; i++)
#pragma unroll
        for (int j = 0; j < 4; j++) acc[i][j] = (f32x4){0.f, 0.f, 0.f, 0.f};

    float4 ar[8];
    float mn, rs;
    float4 s0v, s1v, b0v, b1v;

#define LOADA(kt) do { _Pragma("unroll")                                          \
    for (int i_ = 0; i_ < 4; ++i_) {                                              \
        ar[2 * i_]     = *(const float4*)(xb + (kt) * 64 + (size_t)i_ * 512);     \
        ar[2 * i_ + 1] = *(const float4*)(xb + (kt) * 64 + (size_t)i_ * 512 + 4); \
    } } while (0)

#define LOADP(kt) do { int c0_ = (kt) * 64 + c8 * 8; int bg_ = bg0 + (c0_ >> 4);  \
    mn = mean[bg_]; rs = rstd[bg_];                                               \
    s0v = *(const float4*)(gns + c0_); s1v = *(const float4*)(gns + c0_ + 4);     \
    b0v = *(const float4*)(gnb + c0_); b1v = *(const float4*)(gnb + c0_ + 4);     \
  } while (0)

#define WRITEA(nbuf) do {                                                         \
    float m2_[8], a2_[8];                                                         \
    m2_[0]=rs*s0v.x; m2_[1]=rs*s0v.y; m2_[2]=rs*s0v.z; m2_[3]=rs*s0v.w;           \
    m2_[4]=rs*s1v.x; m2_[5]=rs*s1v.y; m2_[6]=rs*s1v.z; m2_[7]=rs*s1v.w;           \
    a2_[0]=b0v.x-mn*m2_[0]; a2_[1]=b0v.y-mn*m2_[1];                               \
    a2_[2]=b0v.z-mn*m2_[2]; a2_[3]=b0v.w-mn*m2_[3];                               \
    a2_[4]=b1v.x-mn*m2_[4]; a2_[5]=b1v.y-mn*m2_[5];                               \
    a2_[6]=b1v.z-mn*m2_[6]; a2_[7]=b1v.w-mn*m2_[7];                               \
    _Pragma("unroll")                                                             \
    for (int i_ = 0; i_ < 4; ++i_) {                                              \
        int row_ = rbase + i_;                                                    \
        bf16x8 pk_;                                                               \
        pk_[0]=(short)f2bf(ar[2*i_].x  *m2_[0]+a2_[0]);                           \
        pk_[1]=(short)f2bf(ar[2*i_].y  *m2_[1]+a2_[1]);                           \
        pk_[2]=(short)f2bf(ar[2*i_].z  *m2_[2]+a2_[2]);                           \
        pk_[3]=(short)f2bf(ar[2*i_].w  *m2_[3]+a2_[3]);                           \
        pk_[4]=(short)f2bf(ar[2*i_+1].x*m2_[4]+a2_[4]);                           \
        pk_[5]=(short)f2bf(ar[2*i_+1].y*m2_[5]+a2_[5]);                           \
        pk_[6]=(short)f2bf(ar[2*i_+1].z*m2_[6]+a2_[6]);                           \
        pk_[7]=(short)f2bf(ar[2*i_+1].w*m2_[7]+a2_[7]);                           \
        *(bf16x8*)&LA[nbuf][row_ * 64 + ((c8 ^ (row_ & 7)) * 8)] = pk_;           \
    } } while (0)

#define STG_B(kt, s) __builtin_amdgcn_global_load_lds( \
        (const AS1 void*)(gB + (kt) * 64 + (size_t)((s) * 32) * K), \
        (AS3 void*)(&LB[(kt) & 1][(s) * 2048 + lo]), 16, 0, 0)

#define PHASE_(buf, h, ks) do {                                                            \
    bf16x8 afr[2], bfr[4];                                                                 \
    const int ch_ = (((ks) * 4 + q) ^ (r16 & 7)) * 8;                                      \
    _Pragma("unroll")                                                                      \
    for (int mi = 0; mi < 2; mi++)                                                         \
        afr[mi] = *(const bf16x8*)&LA[buf][(wr * 64 + ((h) * 2 + mi) * 16 + r16) * 64 + ch_]; \
    _Pragma("unroll")                                                                      \
    for (int ni = 0; ni < 4; ni++)                                                         \
        bfr[ni] = *(const bf16x8*)&LB[buf][(wc * 64 + ni * 16 + r16) * 64 + ch_];          \
    __builtin_amdgcn_s_setprio(1);                                                         \
    _Pragma("unroll")                                                                      \
    for (int mi = 0; mi < 2; mi++)                                                         \
      _Pragma("unroll")                                                                    \
      for (int ni = 0; ni < 4; ni++)                                                       \
        acc[(h) * 2 + mi][ni] =                                                            \
            __builtin_amdgcn_mfma_f32_16x16x32_bf16(afr[mi], bfr[ni], acc[(h) * 2 + mi][ni], 0, 0, 0); \
    __builtin_amdgcn_s_setprio(0);                                                         \
  } while (0)

    LOADA(0); LOADP(0);
    asm volatile("" ::: "memory");
    STG_B(0, 0); STG_B(0, 1); STG_B(0, 2); STG_B(0, 3);
    asm volatile("s_waitcnt vmcnt(4)" ::: "memory");
    WRITEA(0);
    asm volatile("s_waitcnt lgkmcnt(0)" ::: "memory");

#pragma unroll
    for (int t = 0; t < 7; ++t) {
        const int buf = t & 1;
        LOADA(t + 1); LOADP(t + 1);
        asm volatile("" ::: "memory");
        STG_B(t + 1, 0); STG_B(t + 1, 1); STG_B(t + 1, 2); STG_B(t + 1, 3);
        asm volatile("s_waitcnt vmcnt(18)" ::: "memory");
        __builtin_amdgcn_s_barrier();
        asm volatile("" ::: "memory");
        PHASE_(buf, 0, 0); PHASE_(buf, 1, 0); PHASE_(buf, 0, 1); PHASE_(buf, 1, 1);
        asm volatile("s_waitcnt vmcnt(4)" ::: "memory");
        WRITEA(buf ^ 1);
        asm volatile("s_waitcnt lgkmcnt(0)" ::: "memory");
        __builtin_amdgcn_s_barrier();
        asm volatile("" ::: "memory");
    }
    asm volatile("s_waitcnt vmcnt(0) lgkmcnt(0)" ::: "memory");
    __builtin_amdgcn_s_barrier();
    asm volatile("" ::: "memory");
    PHASE_(1, 0, 0); PHASE_(1, 1, 0); PHASE_(1, 0, 1); PHASE_(1, 1, 1);
#undef LOADA
#undef LOADP
#undef WRITEA
#undef STG_B
#undef PHASE_

#pragma unroll
    for (int mi = 0; mi < 4; mi++) {
#pragma unroll
        for (int rr = 0; rr < 4; rr++) {
            int grow = row0 + wr * 64 + mi * 16 + q * 4 + rr;
#pragma unroll
            for (int ni = 0; ni < 4; ni++) {
                int gcol = col0 + wc * 64 + ni * 16 + r16;
                float v = acc[mi][ni][rr] + bias[gcol];
                out[(size_t)grow * 512 + gcol] = f2bf(v);
            }
        }
    }
}

// ------- O-proj GEMM (r13/r17 best): 128x128, BK=32, dbuf 32KB LDS, __launch_bounds__(256,4) -------
__global__ __launch_bounds__(256, 4) void gemm_ring(const u16* __restrict__ A,
                                                    const u16* __restrict__ Bt,
                                                    const float* __restrict__ bias,
                                                    const float* __restrict__ res,
                                                    float* __restrict__ out) {
    constexpr int K = 512;
    __shared__ __align__(16) u16 LA[2][4096];
    __shared__ __align__(16) u16 LB[2][4096];
    int tid = threadIdx.x, lane = tid & 63, wid = tid >> 6;
    int wr = wid >> 1, wc = wid & 1;
    int q = lane >> 4, r16 = lane & 15;

    int orig = blockIdx.x;
    int wg = (orig & 7) * 256 + (orig >> 3);
    int bx = wg & 3, by = wg >> 2;
    int row0 = by * 128, col0 = bx * 128;

    int srow = tid >> 2;
    int schunk = (tid & 3) ^ (srow & 3);
    const u16* gA = A + (size_t)(row0 + srow) * K + schunk * 8;
    const u16* gB = Bt + (size_t)(col0 + srow) * K + schunk * 8;
    const int lo = tid * 8;

    f32x4 acc[4][4];
#pragma unroll
    for (int i = 0; i < 4; i++)
#pragma unroll
        for (int j = 0; j < 4; j++) acc[i][j] = (f32x4){0.f, 0.f, 0.f, 0.f};

#define STG(kt) do { int sl_ = (kt) & 1;                                              \
    __builtin_amdgcn_global_load_lds((const AS1 void*)(gA + (kt) * 32),               \
                                     (AS3 void*)(&LA[sl_][lo]), 16, 0, 0);            \
    __builtin_amdgcn_global_load_lds((const AS1 void*)(gA + (kt) * 32 + (size_t)64 * K), \
                                     (AS3 void*)(&LA[sl_][2048 + lo]), 16, 0, 0);     \
    __builtin_amdgcn_global_load_lds((const AS1 void*)(gB + (kt) * 32),               \
                                     (AS3 void*)(&LB[sl_][lo]), 16, 0, 0);            \
    __builtin_amdgcn_global_load_lds((const AS1 void*)(gB + (kt) * 32 + (size_t)64 * K), \
                                     (AS3 void*)(&LB[sl_][2048 + lo]), 16, 0, 0);     \
  } while (0)

#define COMPUTE(sl) do {                                                              \
    bf16x8 afr[4], bfr[4];                                                            \
    const int ch_ = (q ^ (r16 & 3)) * 8;                                              \
    _Pragma("unroll")                                                                 \
    for (int mi = 0; mi < 4; mi++)                                                    \
        afr[mi] = *(const bf16x8*)&LA[sl][(wr * 64 + mi * 16 + r16) * 32 + ch_];      \
    _Pragma("unroll")                                                                 \
    for (int ni = 0; ni < 4; ni++)                                                    \
        bfr[ni] = *(const bf16x8*)&LB[sl][(wc * 64 + ni * 16 + r16) * 32 + ch_];      \
    __builtin_amdgcn_s_setprio(1);                                                    \
    _Pragma("unroll")                                                                 \
    for (int mi = 0; mi < 4; mi++)                                                    \
      _Pragma("unroll")                                                               \
      for (int ni = 0; ni < 4; ni++)                                                  \
        acc[mi][ni] = __builtin_amdgcn_mfma_f32_16x16x32_bf16(afr[mi], bfr[ni], acc[mi][ni], 0, 0, 0); \
    __builtin_amdgcn_s_setprio(0);                                                    \
  } while (0)

    STG(0);
#pragma unroll
    for (int t = 0; t < 15; ++t) {
        STG(t + 1);
        asm volatile("s_waitcnt vmcnt(4)" ::: "memory");
        asm volatile("s_barrier" ::: "memory");
        COMPUTE(t & 1);
        asm volatile("s_barrier" ::: "memory");
    }
    asm volatile("s_waitcnt vmcnt(0)" ::: "memory");
    asm volatile("s_barrier" ::: "memory");
    COMPUTE(1);
#undef STG
#undef COMPUTE

#pragma unroll
    for (int mi = 0; mi < 4; mi++) {
#pragma unroll
        for (int rr = 0; rr < 4; rr++) {
            int grow = row0 + wr * 64 + mi * 16 + q * 4 + rr;
#pragma unroll
            for (int ni = 0; ni < 4; ni++) {
                int gcol = col0 + wc * 64 + ni * 16 + r16;
                float v = acc[mi][ni][rr] + bias[gcol];
                size_t idx = (size_t)grow * 512 + gcol;
                out[idx] = v + res[idx];
            }
        }
    }
}

// ------- MFMA cross-attention: 8 Q-tiles per block (r13 best config), K/V staged once -------
__global__ __launch_bounds__(256) void attn_mfma(const u16* __restrict__ Qb,
                                                 const u16* __restrict__ Kb,
                                                 const u16* __restrict__ Vb,
                                                 u16* __restrict__ Ob) {
    __shared__ __align__(16) u16 Ks[80][72];    // [ctx][d]
    __shared__ __align__(16) u16 VT[64][104];   // [d][ctx]
    __shared__ __align__(16) u16 Ps[64][104];   // [qrow_local][ctx]
    int tid = threadIdx.x, lane = tid & 63, wv = tid >> 6;
    int q = lane >> 4, r16 = lane & 15;
    int tile0 = blockIdx.x * 8;
    int bh = blockIdx.y;
    int b = bh >> 3, h = bh & 7;

    {
        unsigned* p0 = (unsigned*)&Ks[0][0];
        for (int i = tid; i < 2880; i += 256) p0[i] = 0u;
        unsigned* p1 = (unsigned*)&VT[0][0];
        for (int i = tid; i < 3328; i += 256) p1[i] = 0u;
        unsigned* p2 = (unsigned*)&Ps[0][0];
        for (int i = tid; i < 3328; i += 256) p2[i] = 0u;
    }
    __syncthreads();

    size_t kvbase = ((size_t)b * NCTX) * C_ + h * HD;
    for (int c = tid; c < NCTX * 8; c += 256) {
        int j = c >> 3, d8 = (c & 7) * 8;
        *(bf16x8*)&Ks[j][d8] = *(const bf16x8*)(Kb + kvbase + (size_t)j * C_ + d8);
    }
    for (int t = tid; t < NCTX * 64; t += 256) {
        int j = t >> 6, d = t & 63;
        VT[d][j] = Vb[kvbase + (size_t)j * C_ + d];
    }
    __syncthreads();

    const size_t tstep = (size_t)64 * C_;
    const u16* qp = Qb + ((size_t)b * HW_ + wv * 16 + r16) * C_ + h * HD + q * 8;
    bool v4 = (r16 < NCTX - 64);

    bf16x8 qc0 = *(const bf16x8*)(qp + (size_t)tile0 * tstep);
    bf16x8 qc1 = *(const bf16x8*)(qp + (size_t)tile0 * tstep + 32);

    for (int it = 0; it < 8; ++it) {
        int tile = tile0 + it;
        bf16x8 qn0 = qc0, qn1 = qc1;
        if (it < 7) {
            qn0 = *(const bf16x8*)(qp + (size_t)(tile + 1) * tstep);
            qn1 = *(const bf16x8*)(qp + (size_t)(tile + 1) * tstep + 32);
        }

        f32x4 accs[5];
#pragma unroll
        for (int nt = 0; nt < 5; ++nt) accs[nt] = (f32x4){0.f, 0.f, 0.f, 0.f};
#pragma unroll
        for (int nt = 0; nt < 5; ++nt) {
            bf16x8 kf = *(const bf16x8*)&Ks[nt * 16 + r16][q * 8];
            accs[nt] = __builtin_amdgcn_mfma_f32_16x16x32_bf16(qc0, kf, accs[nt], 0, 0, 0);
        }
#pragma unroll
        for (int nt = 0; nt < 5; ++nt) {
            bf16x8 kf = *(const bf16x8*)&Ks[nt * 16 + r16][32 + q * 8];
            accs[nt] = __builtin_amdgcn_mfma_f32_16x16x32_bf16(qc1, kf, accs[nt], 0, 0, 0);
        }

#pragma unroll
        for (int r = 0; r < 4; ++r) {
            float s[5];
#pragma unroll
            for (int nt = 0; nt < 5; ++nt) s[nt] = accs[nt][r] * 0.125f;
            float m = fmaxf(fmaxf(fmaxf(s[0], s[1]), fmaxf(s[2], s[3])), v4 ? s[4] : -3.0e38f);
#pragma unroll
            for (int off = 1; off < 16; off <<= 1) m = fmaxf(m, __shfl_xor(m, off));
            float e[5], sum = 0.f;
#pragma unroll
            for (int nt = 0; nt < 5; ++nt) {
                e[nt] = (nt < 4 || v4) ? __expf(s[nt] - m) : 0.f;
                sum += e[nt];
            }
#pragma unroll
            for (int off = 1; off < 16; off <<= 1) sum += __shfl_xor(sum, off);
            float inv = 1.0f / sum;
            int prow = wv * 16 + q * 4 + r;
#pragma unroll
            for (int nt = 0; nt < 5; ++nt)
                Ps[prow][nt * 16 + r16] = f2bf(e[nt] * inv);
        }

        f32x4 acco[4];
#pragma unroll
        for (int nt = 0; nt < 4; ++nt) acco[nt] = (f32x4){0.f, 0.f, 0.f, 0.f};
#pragma unroll
        for (int ks = 0; ks < 3; ++ks) {
            bf16x8 pf = *(const bf16x8*)&Ps[wv * 16 + r16][ks * 32 + q * 8];
#pragma unroll
            for (int nt = 0; nt < 4; ++nt) {
                bf16x8 vf = *(const bf16x8*)&VT[nt * 16 + r16][ks * 32 + q * 8];
                acco[nt] = __builtin_amdgcn_mfma_f32_16x16x32_bf16(pf, vf, acco[nt], 0, 0, 0);
            }
        }

        int row0 = tile * 64 + wv * 16;
#pragma unroll
        for (int nt = 0; nt < 4; ++nt)
#pragma unroll
            for (int r = 0; r < 4; ++r) {
                int row = row0 + q * 4 + r;
                int col = h * HD + nt * 16 + r16;
                Ob[((size_t)b * HW_ + row) * C_ + col] = f2bf(acco[nt][r]);
            }
        qc0 = qn0; qc1 = qn1;
    }
}

extern "C" void kernel_launch(void* const* d_in, const int* in_sizes, int n_in,
                              void* d_out, int out_size, void* d_ws, size_t ws_size,
                              hipStream_t stream) {
    const float* x   = (const float*)d_in[0];
    const float* ctx = (const float*)d_in[1];
    const float* gns = (const float*)d_in[2];
    const float* gnb = (const float*)d_in[3];
    const float* wq  = (const float*)d_in[4];
    const float* bq  = (const float*)d_in[5];
    const float* wk  = (const float*)d_in[6];
    const float* bk  = (const float*)d_in[7];
    const float* wv  = (const float*)d_in[8];
    const float* bv  = (const float*)d_in[9];
    const float* wo  = (const float*)d_in[10];
    const float* bo  = (const float*)d_in[11];

    char* ws = (char*)d_ws;
    float* mean = (float*)(ws + 0);          // 512 f
    float* rstd = (float*)(ws + 2048);       // 512 f
    u16* wqT  = (u16*)(ws + 4096);           // 512*512
    u16* wkT  = (u16*)(ws + 528384);         // 512*768
    u16* wvT  = (u16*)(ws + 1314816);        // 512*768
    u16* woT  = (u16*)(ws + 2101248);        // 512*512
    u16* aob  = (u16*)(ws + 4517888);        // 65536*512 (attn out)
    u16* qb   = (u16*)(ws + 71626752);       // 65536*512
    u16* kb   = (u16*)(ws + 138735616);      // 1232*512
    u16* vb   = (u16*)(ws + 139997184);      // 1232*512

    gn_trans<<<5632, 256, 0, stream>>>(x, mean, rstd, wq, wk, wv, wo, wqT, wkT, wvT, woT);

    gemm_fusedq<<<2128, 256, 0, stream>>>(x, mean, rstd, gns, gnb, wqT, bq, qb,
                                          ctx, wkT, wvT, bk, bv, kb, vb);

    attn_mfma<<<dim3(8, 128), 256, 0, stream>>>(qb, kb, vb, aob);

    gemm_ring<<<2048, 256, 0, stream>>>(aob, woT, bo, x, (float*)d_out);
}